// Round 16
// baseline (511.640 us; speedup 1.0000x reference)
//
#include <hip/hip_runtime.h>

typedef _Float16 f16;
typedef _Float16 f16x4 __attribute__((ext_vector_type(4)));
typedef _Float16 f16x8 __attribute__((ext_vector_type(8)));
typedef float    f32x4 __attribute__((ext_vector_type(4)));

#define MFMA(a,b,c) __builtin_amdgcn_mfma_f32_16x16x32_f16(a,b,c,0,0,0)
#define SBAR() __builtin_amdgcn_sched_barrier(0)
#define BARRIER() do { SBAR(); __builtin_amdgcn_s_barrier(); SBAR(); } while (0)
#define VMCNT(n) do { SBAR(); asm volatile("s_waitcnt vmcnt(" #n ")" ::: "memory"); SBAR(); } while (0)
#define LGKM0() do { asm volatile("s_waitcnt lgkmcnt(0)" ::: "memory"); SBAR(); } while (0)

__device__ __forceinline__ void gload_lds16(const f16* g, f16* l) {
  __builtin_amdgcn_global_load_lds(
      (const __attribute__((address_space(1))) unsigned int*)g,
      (__attribute__((address_space(3))) unsigned int*)l, 16, 0, 0);
}

// ---------------------------------------------------------------------------
// f32 -> f16 convert for BOTH weight matrices in one dispatch (y decodes)
// ---------------------------------------------------------------------------
__global__ __launch_bounds__(256)
void tof16x2_kernel(const float* __restrict__ w1, const float* __restrict__ w2,
                    f16* __restrict__ y1, f16* __restrict__ y2, int n4) {
  int i = blockIdx.x * 256 + threadIdx.x;
  if (i >= n4) return;
  const float* x = blockIdx.y ? w2 : w1;
  f16* y = blockIdx.y ? y2 : y1;
  f32x4 v = ((const f32x4*)x)[i];
  f16x4 h;
#pragma unroll
  for (int j = 0; j < 4; j++) h[j] = (f16)v[j];
  ((f16x4*)y)[i] = h;
}

// ---------------------------------------------------------------------------
// Fused convert + transpose for BOTH S chunks in one dispatch (z decodes)
// ---------------------------------------------------------------------------
__global__ __launch_bounds__(256)
void prep2_f16_kernel(const float* __restrict__ s1, const float* __restrict__ s2,
                      f16* __restrict__ rm1, f16* __restrict__ tr1,
                      f16* __restrict__ rm2, f16* __restrict__ tr2, int bc) {
  __shared__ f16 t[64][68];
  const int tid = threadIdx.x;
  const int zz = blockIdx.z;
  const int sel = zz >= bc;
  const size_t z = sel ? (zz - bc) : zz;
  const float* in = sel ? s2 : s1;
  f16* rm = sel ? rm2 : rm1;
  f16* tr = sel ? tr2 : tr1;
  const int n0 = blockIdx.x * 64, h0 = blockIdx.y * 64;
  const int rr = tid >> 4, cc = (tid & 15) * 4;
#pragma unroll
  for (int p = 0; p < 4; p++) {
    int n = rr + p * 16;
    f32x4 v = *(const f32x4*)(in + ((size_t)z * 2048 + n0 + n) * 1024 + h0 + cc);
    f16x4 h;
#pragma unroll
    for (int j = 0; j < 4; j++) h[j] = (f16)v[j];
    *(f16x4*)&t[n][cc] = h;
    *(f16x4*)(rm + ((size_t)z * 2048 + n0 + n) * 1024 + h0 + cc) = h;
  }
  __syncthreads();
#pragma unroll
  for (int p = 0; p < 4; p++) {
    int h = rr + p * 16;
    f16x4 o;
#pragma unroll
    for (int j = 0; j < 4; j++) o[j] = t[cc + j][h];
    *(f16x4*)(tr + ((size_t)z * 1024 + h0 + h) * 2048 + n0 + cc) = o;
  }
}

// ---------------------------------------------------------------------------
// 256x256-tile 4-phase GEMM (r7 schedule), three modes:
//  MODE 0 (proj):   C f16 = A*B^T
//  MODE 1 (scores): writes Eb f16 = exp(acc - M_b) per element, plus per-
//                   (row, by-block) partials Pp = {M_b, S_b} (float2).
//                   M_b = block-row max (in-reg shfl + LDS combine over wn);
//                   S_b = block-row sum of f32 exp.
//  MODE 2 (PV):     A-fragments scaled by per-(row, K-block) f16 factor
//                   Cb[row][b] = exp(M_b - m)/s  (b = kt>>8); C f32.
// Block mapping (batch-per-XCD): z = id % ZB, k = id / ZB; bx=k%gx, by=k/gx.
// ---------------------------------------------------------------------------
template <int MODE>
__global__ __launch_bounds__(512, 2)
void gemm256(const f16* __restrict__ Ag, size_t zA,
             const f16* __restrict__ Bg, size_t zB,
             void* __restrict__ Cg, size_t zC,
             float2* __restrict__ Pp, const f16* __restrict__ Cbp,
             int lda, int ldb, int ldc, int K, int ZB, int gx) {
  __shared__ f16 sm[8][8192];  // [c*4 + mat*2 + kk][256*32], 128 KB
  const int tid = threadIdx.x;
  const int id = blockIdx.x;
  const size_t z = id % ZB;
  const int k = id / ZB;
  const int bx = k % gx, by = k / gx;
  const f16* A = Ag + z * zA + (size_t)bx * 256 * lda;
  const f16* B = Bg + z * zB + (size_t)by * 256 * ldb;

  const int lane = tid & 63, w = tid >> 6;
  const int wm = w >> 2, wn = w & 3;
  const int lr = lane & 15, kg = lane >> 4;
  const int sx = (kg ^ ((lr >> 1) & 3)) << 3;      // swizzled chunk for reads
  const int aoff = wm * 4096 + lr * 32 + sx;
  const int boff = wn * 2048 + lr * 32 + sx;
  const int colx = (((tid & 3) ^ ((tid >> 3) & 3)) << 3);  // pre-swizzled src col
  const int srow = tid >> 2;
  const int wls = w * 512;  // wave-uniform LDS base (halfs) per issue

  f32x4 acc[8][4] = {};
  f16x8 af[8], bf0, bf1;
  f16 cf[8];  // MODE 2: per-row scale for current K-block
  const f16* cbbase = nullptr;
  if (MODE == 2)
    cbbase = Cbp + ((size_t)z * 2048 + (size_t)bx * 256 + wm * 128 + lr) * 8;

#define STAGE(cc, mat, kkv, ktc) do {                                          \
    const f16* gs = ((mat) ? B : A) + (size_t)srow * ((mat) ? ldb : lda) +     \
                    (ktc) + (kkv) * 32 + colx;                                 \
    f16* ls = &sm[(cc) * 4 + (mat) * 2 + (kkv)][wls];                          \
    gload_lds16(gs, ls);                                                       \
    gload_lds16(gs + (size_t)128 * ((mat) ? ldb : lda), ls + 4096);            \
  } while (0)

#define LOAD_A(cc, kkv) do { _Pragma("unroll")                                 \
    for (int fm = 0; fm < 8; fm++)                                             \
      af[fm] = *(const f16x8*)&sm[(cc) * 4 + (kkv)][aoff + fm * 512];          \
  } while (0)

#define MULA() do { if (MODE == 2) { _Pragma("unroll")                         \
    for (int fm = 0; fm < 8; fm++) af[fm] = af[fm] * cf[fm]; } } while (0)

#define LOAD_B(cc, kkv, nh) do {                                               \
    bf0 = *(const f16x8*)&sm[(cc) * 4 + 2 + (kkv)][boff + (nh) * 1024];        \
    bf1 = *(const f16x8*)&sm[(cc) * 4 + 2 + (kkv)][boff + (nh) * 1024 + 512];  \
  } while (0)

#define DOMFMA(nh) do {                                                        \
    __builtin_amdgcn_s_setprio(1);                                             \
    _Pragma("unroll")                                                          \
    for (int fm = 0; fm < 8; fm++) {                                           \
      acc[fm][(nh) * 2]     = MFMA(af[fm], bf0, acc[fm][(nh) * 2]);            \
      acc[fm][(nh) * 2 + 1] = MFMA(af[fm], bf1, acc[fm][(nh) * 2 + 1]);        \
    }                                                                          \
    __builtin_amdgcn_s_setprio(0);                                             \
    SBAR();                                                                    \
  } while (0)

#define LOADCF(t) do { if (MODE == 2 && (((t) & 3) == 0)) { _Pragma("unroll")  \
    for (int fm = 0; fm < 8; fm++) cf[fm] = cbbase[fm * 128 + ((t) >> 2)]; }   \
  } while (0)

  const int nt = K >> 6;
  // prologue
  STAGE(0, 0, 0, 0);
  STAGE(0, 1, 0, 0);
  STAGE(0, 0, 1, 0);
  STAGE(0, 1, 1, 0);
  LOADCF(0);
  VMCNT(4);
  BARRIER();

  for (int t = 0; t < nt - 1; ++t) {
    const int c = t & 1;
    const int kt1 = (t + 1) << 6;
    // ph0
    LOADCF(t);
    LOAD_A(c, 0); LOAD_B(c, 0, 0);
    STAGE(c ^ 1, 0, 0, kt1);
    BARRIER();
    LGKM0();
    MULA();
    DOMFMA(0);
    BARRIER();
    // ph1
    LOAD_B(c, 0, 1);
    STAGE(c ^ 1, 1, 0, kt1);
    BARRIER();
    LGKM0();
    DOMFMA(1);
    VMCNT(4);
    BARRIER();
    // ph2
    LOAD_A(c, 1); LOAD_B(c, 1, 0);
    STAGE(c ^ 1, 0, 1, kt1);
    BARRIER();
    LGKM0();
    MULA();
    DOMFMA(0);
    BARRIER();
    // ph3
    LOAD_B(c, 1, 1);
    STAGE(c ^ 1, 1, 1, kt1);
    BARRIER();
    LGKM0();
    DOMFMA(1);
    VMCNT(4);
    BARRIER();
  }
  {  // last tile
    const int c = (nt - 1) & 1;
    LOADCF(nt - 1);
    LOAD_A(c, 0); LOAD_B(c, 0, 0);
    BARRIER();
    LGKM0();
    MULA();
    DOMFMA(0);
    BARRIER();
    LOAD_B(c, 0, 1);
    BARRIER();
    LGKM0();
    DOMFMA(1);
    VMCNT(0);
    BARRIER();
    LOAD_A(c, 1); LOAD_B(c, 1, 0);
    BARRIER();
    LGKM0();
    MULA();
    DOMFMA(0);
    BARRIER();
    LOAD_B(c, 1, 1);
    BARRIER();
    LGKM0();
    DOMFMA(1);
  }

  if (MODE == 0 || MODE == 2) {
#pragma unroll
    for (int fm = 0; fm < 8; fm++)
#pragma unroll
      for (int fn = 0; fn < 4; fn++)
#pragma unroll
        for (int q = 0; q < 4; q++) {
          size_t grow = (size_t)bx * 256 + wm * 128 + fm * 16 + kg * 4 + q;
          int gcol = by * 256 + wn * 64 + fn * 16 + lr;
          if (MODE == 2)
            ((float*)Cg)[z * zC + grow * ldc + gcol] = acc[fm][fn][q];
          else
            ((f16*)Cg)[z * zC + grow * ldc + gcol] = (f16)acc[fm][fn][q];
        }
  } else {
    // MODE 1: block-softmax epilogue.  red1/red2: [2 wm][128 row][4 wn] f32.
    float* red1 = (float*)&sm[0][0];
    float* red2 = red1 + 1024;
    // Phase A: block-row max
    float mx[8][4];
#pragma unroll
    for (int fm = 0; fm < 8; fm++)
#pragma unroll
      for (int q = 0; q < 4; q++) {
        float m0 = fmaxf(fmaxf(acc[fm][0][q], acc[fm][1][q]),
                         fmaxf(acc[fm][2][q], acc[fm][3][q]));
#pragma unroll
        for (int off = 1; off < 16; off <<= 1) m0 = fmaxf(m0, __shfl_xor(m0, off));
        mx[fm][q] = m0;
      }
    BARRIER();  // K-loop LDS reads fully drained (LGKM0 per phase)
    if (lr == 0) {
#pragma unroll
      for (int fm = 0; fm < 8; fm++)
#pragma unroll
        for (int q = 0; q < 4; q++)
          red1[wm * 512 + (fm * 16 + kg * 4 + q) * 4 + wn] = mx[fm][q];
    }
    BARRIER();
    float M[8][4];
#pragma unroll
    for (int fm = 0; fm < 8; fm++)
#pragma unroll
      for (int q = 0; q < 4; q++) {
        int row = fm * 16 + kg * 4 + q;
        M[fm][q] = fmaxf(fmaxf(red1[wm * 512 + row * 4 + 0],
                               red1[wm * 512 + row * 4 + 1]),
                         fmaxf(red1[wm * 512 + row * 4 + 2],
                               red1[wm * 512 + row * 4 + 3]));
      }
    // Phase B: exp, store Eb, block-row sums
    float sp[8][4] = {};
#pragma unroll
    for (int fm = 0; fm < 8; fm++)
#pragma unroll
      for (int fn = 0; fn < 4; fn++)
#pragma unroll
        for (int q = 0; q < 4; q++) {
          float e = __expf(acc[fm][fn][q] - M[fm][q]);
          sp[fm][q] += e;
          size_t grow = (size_t)bx * 256 + wm * 128 + fm * 16 + kg * 4 + q;
          int gcol = by * 256 + wn * 64 + fn * 16 + lr;
          ((f16*)Cg)[z * zC + grow * ldc + gcol] = (f16)e;
        }
#pragma unroll
    for (int fm = 0; fm < 8; fm++)
#pragma unroll
      for (int q = 0; q < 4; q++) {
        float s0 = sp[fm][q];
#pragma unroll
        for (int off = 1; off < 16; off <<= 1) s0 += __shfl_xor(s0, off);
        sp[fm][q] = s0;
      }
    BARRIER();
    if (lr == 0) {
#pragma unroll
      for (int fm = 0; fm < 8; fm++)
#pragma unroll
        for (int q = 0; q < 4; q++)
          red2[wm * 512 + (fm * 16 + kg * 4 + q) * 4 + wn] = sp[fm][q];
    }
    BARRIER();
    if (wn == 0 && lr == 0) {
#pragma unroll
      for (int fm = 0; fm < 8; fm++)
#pragma unroll
        for (int q = 0; q < 4; q++) {
          int row = fm * 16 + kg * 4 + q;
          float S = red2[wm * 512 + row * 4 + 0] + red2[wm * 512 + row * 4 + 1] +
                    red2[wm * 512 + row * 4 + 2] + red2[wm * 512 + row * 4 + 3];
          size_t grow = (size_t)bx * 256 + wm * 128 + row;
          float2 pv; pv.x = M[fm][q]; pv.y = S;
          Pp[(z * 2048 + grow) * 8 + by] = pv;
        }
    }
  }
#undef STAGE
#undef LOAD_A
#undef MULA
#undef LOAD_B
#undef DOMFMA
#undef LOADCF
}

// ---------------------------------------------------------------------------
// Combine per-block partials: per row, m = max M_b; s = sum S_b*exp(M_b-m);
// Cb[row][b] = f16(exp(M_b - m) / s).
// ---------------------------------------------------------------------------
__global__ __launch_bounds__(256)
void combine_msum(const float2* __restrict__ Pp, f16* __restrict__ Cb, int nrows) {
  int r = blockIdx.x * 256 + threadIdx.x;
  if (r >= nrows) return;
  const float2* p = Pp + (size_t)r * 8;
  float2 pb[8];
#pragma unroll
  for (int b = 0; b < 8; b++) pb[b] = p[b];
  float m = pb[0].x;
#pragma unroll
  for (int b = 1; b < 8; b++) m = fmaxf(m, pb[b].x);
  float s = 0.f;
#pragma unroll
  for (int b = 0; b < 8; b++) s += pb[b].y * __expf(pb[b].x - m);
  float inv = 1.0f / s;
  f16x8 o;
#pragma unroll
  for (int b = 0; b < 8; b++) o[b] = (f16)(__expf(pb[b].x - m) * inv);
  *(f16x8*)(Cb + (size_t)r * 8) = o;
}

// ---------------------------------------------------------------------------
extern "C" void kernel_launch(void* const* d_in, const int* in_sizes, int n_in,
                              void* d_out, int out_size, void* d_ws, size_t ws_size,
                              hipStream_t stream) {
  const float* S1 = (const float*)d_in[0];
  const float* S2 = (const float*)d_in[1];
  const float* W1 = (const float*)d_in[2];
  const float* W2 = (const float*)d_in[3];
  float* out = (float*)d_out;
  const int B = 8, N = 2048, H = 1024;
  const size_t NH = (size_t)N * H;  // 2M elems
  const size_t NN = (size_t)N * N;  // 4M elems
  const size_t WN = (size_t)H * H;  // 1M elems

  char* ws = (char*)d_ws;
  f16* W1h = (f16*)ws;
  f16* W2h = W1h + WN;
  size_t fixed = 2 * WN * sizeof(f16);  // 4 MB
  // per-batch: Ah,Bh,At,Bt,Kh (5*NH f16) + Eb (NN f16) + Pp (2048*8 float2)
  //            + Cb (2048*8 f16)
  size_t perb = 5 * NH * sizeof(f16) + NN * sizeof(f16) +
                (size_t)N * 8 * sizeof(float2) + (size_t)N * 8 * sizeof(f16);

  int bc = 1;
  const int cands[4] = {8, 4, 2, 1};
  for (int ci = 0; ci < 4; ci++) {
    if (fixed + (size_t)cands[ci] * perb <= ws_size) { bc = cands[ci]; break; }
  }
  f16* Ah = (f16*)(ws + fixed);       // S1 chunk f16
  f16* Bh = Ah + (size_t)bc * NH;     // S2 chunk f16
  f16* At = Bh + (size_t)bc * NH;     // S1^T f16 [z][1024][2048]
  f16* Bt = At + (size_t)bc * NH;     // S2^T
  f16* Kh = Bt + (size_t)bc * NH;     // proj output
  f16* Eb = Kh + (size_t)bc * NH;     // exp(scores - M_b), f16 [z][2048][2048]
  float2* Pp = (float2*)(Eb + (size_t)bc * NN);        // [z*2048][8] {M_b,S_b}
  f16* Cb = (f16*)(Pp + (size_t)bc * N * 8);           // [z*2048][8]

  {
    int n4 = (int)(WN / 4);
    tof16x2_kernel<<<dim3((n4 + 255) / 256, 2), 256, 0, stream>>>(
        W1, W2, W1h, W2h, n4);
  }

  for (int c0 = 0; c0 < B; c0 += bc) {
    prep2_f16_kernel<<<dim3(N / 64, H / 64, 2 * bc), 256, 0, stream>>>(
        S1 + (size_t)c0 * NH, S2 + (size_t)c0 * NH, Ah, At, Bh, Bt, bc);

    for (int path = 0; path < 2; path++) {
      const f16* Qh = path ? Bh : Ah;  // query side (f16)
      const f16* Xh = path ? Ah : Bh;  // proj input (f16)
      const f16* Vt = path ? At : Bt;  // V transposed [z][1024][2048]
      const f16* Wh = path ? W2h : W1h;
      float* Op = out + (size_t)path * B * NH + (size_t)c0 * NH;

      // proj: Kh = Xh @ W^T  (M = bc*2048, N = 1024, K = 1024)
      gemm256<0><<<dim3(bc * 32), 512, 0, stream>>>(
          Xh, 0, Wh, 0, Kh, 0, nullptr, nullptr, H, H, H, H, 1, bc * 8);
      // scores: Eb = f16(exp(Q@Kh^T - M_b)), partials Pp  (per batch 2048^2)
      gemm256<1><<<dim3(bc * 64), 512, 0, stream>>>(
          Qh, NH, Kh, NH, Eb, NN, Pp, nullptr, H, H, N, H, bc, 8);
      // combine partials -> per-(row, block) scale Cb
      combine_msum<<<dim3((bc * N + 255) / 256), 256, 0, stream>>>(
          Pp, Cb, bc * N);
      // PV: O = (Cb-scaled Eb) @ Vt^T  (per batch 2048x1024, K = 2048)
      gemm256<2><<<dim3(bc * 32), 512, 0, stream>>>(
          Eb, NN, Vt, NH, Op, NH, nullptr, Cb, N, N, H, N, bc, 8);
    }
  }
}

// Round 17
// 492.503 us; speedup vs baseline: 1.0389x; 1.0389x over previous
//
#include <hip/hip_runtime.h>

typedef _Float16 f16;
typedef _Float16 f16x4 __attribute__((ext_vector_type(4)));
typedef _Float16 f16x8 __attribute__((ext_vector_type(8)));
typedef float    f32x4 __attribute__((ext_vector_type(4)));

#define MFMA(a,b,c) __builtin_amdgcn_mfma_f32_16x16x32_f16(a,b,c,0,0,0)
#define SBAR() __builtin_amdgcn_sched_barrier(0)
#define BARRIER() do { SBAR(); __builtin_amdgcn_s_barrier(); SBAR(); } while (0)
#define VMCNT(n) do { SBAR(); asm volatile("s_waitcnt vmcnt(" #n ")" ::: "memory"); SBAR(); } while (0)
#define LGKM0() do { asm volatile("s_waitcnt lgkmcnt(0)" ::: "memory"); SBAR(); } while (0)

__device__ __forceinline__ void gload_lds16(const f16* g, f16* l) {
  __builtin_amdgcn_global_load_lds(
      (const __attribute__((address_space(1))) unsigned int*)g,
      (__attribute__((address_space(3))) unsigned int*)l, 16, 0, 0);
}

// ---------------------------------------------------------------------------
// f32 -> f16 convert for BOTH weight matrices in one dispatch (y decodes)
// ---------------------------------------------------------------------------
__global__ __launch_bounds__(256)
void tof16x2_kernel(const float* __restrict__ w1, const float* __restrict__ w2,
                    f16* __restrict__ y1, f16* __restrict__ y2, int n4) {
  int i = blockIdx.x * 256 + threadIdx.x;
  if (i >= n4) return;
  const float* x = blockIdx.y ? w2 : w1;
  f16* y = blockIdx.y ? y2 : y1;
  f32x4 v = ((const f32x4*)x)[i];
  f16x4 h;
#pragma unroll
  for (int j = 0; j < 4; j++) h[j] = (f16)v[j];
  ((f16x4*)y)[i] = h;
}

// ---------------------------------------------------------------------------
// Fused convert + transpose for BOTH S chunks in one dispatch (z decodes):
// in f32 [z][2048][1024] -> rm f16 [z][2048][1024] and tr f16 [z][1024][2048]
// ---------------------------------------------------------------------------
__global__ __launch_bounds__(256)
void prep2_f16_kernel(const float* __restrict__ s1, const float* __restrict__ s2,
                      f16* __restrict__ rm1, f16* __restrict__ tr1,
                      f16* __restrict__ rm2, f16* __restrict__ tr2, int bc) {
  __shared__ f16 t[64][68];
  const int tid = threadIdx.x;
  const int zz = blockIdx.z;
  const int sel = zz >= bc;
  const size_t z = sel ? (zz - bc) : zz;
  const float* in = sel ? s2 : s1;
  f16* rm = sel ? rm2 : rm1;
  f16* tr = sel ? tr2 : tr1;
  const int n0 = blockIdx.x * 64, h0 = blockIdx.y * 64;
  const int rr = tid >> 4, cc = (tid & 15) * 4;
#pragma unroll
  for (int p = 0; p < 4; p++) {
    int n = rr + p * 16;
    f32x4 v = *(const f32x4*)(in + ((size_t)z * 2048 + n0 + n) * 1024 + h0 + cc);
    f16x4 h;
#pragma unroll
    for (int j = 0; j < 4; j++) h[j] = (f16)v[j];
    *(f16x4*)&t[n][cc] = h;
    *(f16x4*)(rm + ((size_t)z * 2048 + n0 + n) * 1024 + h0 + cc) = h;
  }
  __syncthreads();
#pragma unroll
  for (int p = 0; p < 4; p++) {
    int h = rr + p * 16;
    f16x4 o;
#pragma unroll
    for (int j = 0; j < 4; j++) o[j] = t[cc + j][h];
    *(f16x4*)(tr + ((size_t)z * 1024 + h0 + h) * 2048 + n0 + cc) = o;
  }
}

// ---------------------------------------------------------------------------
// 256x256-tile 4-phase GEMM (r7 schedule, best measured: 838 TF):
//   C = A(f16,[M][K],lda) * B(f16,[N][K],ldb)^T
// Block mapping (batch-per-XCD): z = id % ZB (consecutive ids round-robin
// XCDs -> XCD owns batch z), k = id / ZB; bx = k % gx, by = k / gx.
// Schedule: pre-barrier ds_read + 1-unit stage, barrier, lgkmcnt(0),
// setprio+16 MFMA, checkpointed vmcnt(4) (one barrier ahead of the phase
// that reads the guarded unit), barrier.
// ---------------------------------------------------------------------------
template <int OUTF32>
__global__ __launch_bounds__(512, 2)
void gemm256(const f16* __restrict__ Ag, size_t zA,
             const f16* __restrict__ Bg, size_t zB,
             void* __restrict__ Cg, size_t zC,
             int lda, int ldb, int ldc, int K, int ZB, int gx) {
  __shared__ f16 sm[8][8192];  // [c*4 + mat*2 + kk][256*32], 128 KB
  const int tid = threadIdx.x;
  const int id = blockIdx.x;
  const size_t z = id % ZB;
  const int k = id / ZB;
  const int bx = k % gx, by = k / gx;
  const f16* A = Ag + z * zA + (size_t)bx * 256 * lda;
  const f16* B = Bg + z * zB + (size_t)by * 256 * ldb;

  const int lane = tid & 63, w = tid >> 6;
  const int wm = w >> 2, wn = w & 3;
  const int lr = lane & 15, kg = lane >> 4;
  const int sx = (kg ^ ((lr >> 1) & 3)) << 3;      // swizzled chunk for reads
  const int aoff = wm * 4096 + lr * 32 + sx;
  const int boff = wn * 2048 + lr * 32 + sx;
  const int colx = (((tid & 3) ^ ((tid >> 3) & 3)) << 3);  // pre-swizzled src col
  const int srow = tid >> 2;
  const int wls = w * 512;  // wave-uniform LDS base (halfs) per issue

  f32x4 acc[8][4] = {};
  f16x8 af[8], bf0, bf1;

#define STAGE(cc, mat, kkv, ktc) do {                                          \
    const f16* gs = ((mat) ? B : A) + (size_t)srow * ((mat) ? ldb : lda) +     \
                    (ktc) + (kkv) * 32 + colx;                                 \
    f16* ls = &sm[(cc) * 4 + (mat) * 2 + (kkv)][wls];                          \
    gload_lds16(gs, ls);                                                       \
    gload_lds16(gs + (size_t)128 * ((mat) ? ldb : lda), ls + 4096);            \
  } while (0)

#define LOAD_A(cc, kkv) do { _Pragma("unroll")                                 \
    for (int fm = 0; fm < 8; fm++)                                             \
      af[fm] = *(const f16x8*)&sm[(cc) * 4 + (kkv)][aoff + fm * 512];          \
  } while (0)

#define LOAD_B(cc, kkv, nh) do {                                               \
    bf0 = *(const f16x8*)&sm[(cc) * 4 + 2 + (kkv)][boff + (nh) * 1024];        \
    bf1 = *(const f16x8*)&sm[(cc) * 4 + 2 + (kkv)][boff + (nh) * 1024 + 512];  \
  } while (0)

#define DOMFMA(nh) do {                                                        \
    __builtin_amdgcn_s_setprio(1);                                             \
    _Pragma("unroll")                                                          \
    for (int fm = 0; fm < 8; fm++) {                                           \
      acc[fm][(nh) * 2]     = MFMA(af[fm], bf0, acc[fm][(nh) * 2]);            \
      acc[fm][(nh) * 2 + 1] = MFMA(af[fm], bf1, acc[fm][(nh) * 2 + 1]);        \
    }                                                                          \
    __builtin_amdgcn_s_setprio(0);                                             \
    SBAR();                                                                    \
  } while (0)

  const int nt = K >> 6;
  // prologue: stage tile 0 (units A0,B0,A1,B1) into buf 0; guard A0,B0
  STAGE(0, 0, 0, 0);
  STAGE(0, 1, 0, 0);
  STAGE(0, 0, 1, 0);
  STAGE(0, 1, 1, 0);
  VMCNT(4);
  BARRIER();

  for (int t = 0; t < nt - 1; ++t) {
    const int c = t & 1;
    const int kt1 = (t + 1) << 6;
    // ph0: reads A0(t),B0(t) [guarded at t-1.ph3 / prologue]
    LOAD_A(c, 0); LOAD_B(c, 0, 0);
    STAGE(c ^ 1, 0, 0, kt1);
    BARRIER();
    LGKM0();
    DOMFMA(0);
    BARRIER();
    // ph1: reads B0(t); checkpoint guards A1(t),B1(t) for ph2
    LOAD_B(c, 0, 1);
    STAGE(c ^ 1, 1, 0, kt1);
    BARRIER();
    LGKM0();
    DOMFMA(1);
    VMCNT(4);
    BARRIER();
    // ph2: reads A1(t),B1(t)
    LOAD_A(c, 1); LOAD_B(c, 1, 0);
    STAGE(c ^ 1, 0, 1, kt1);
    BARRIER();
    LGKM0();
    DOMFMA(0);
    BARRIER();
    // ph3: reads B1(t); checkpoint guards A0(t+1),B0(t+1) for next ph0
    LOAD_B(c, 1, 1);
    STAGE(c ^ 1, 1, 1, kt1);
    BARRIER();
    LGKM0();
    DOMFMA(1);
    VMCNT(4);
    BARRIER();
  }
  {  // last tile: no staging
    const int c = (nt - 1) & 1;
    LOAD_A(c, 0); LOAD_B(c, 0, 0);
    BARRIER();
    LGKM0();
    DOMFMA(0);
    BARRIER();
    LOAD_B(c, 0, 1);
    BARRIER();
    LGKM0();
    DOMFMA(1);
    VMCNT(0);
    BARRIER();
    LOAD_A(c, 1); LOAD_B(c, 1, 0);
    BARRIER();
    LGKM0();
    DOMFMA(0);
    BARRIER();
    LOAD_B(c, 1, 1);
    BARRIER();
    LGKM0();
    DOMFMA(1);
  }

#pragma unroll
  for (int fm = 0; fm < 8; fm++)
#pragma unroll
    for (int fn = 0; fn < 4; fn++)
#pragma unroll
      for (int q = 0; q < 4; q++) {
        size_t grow = (size_t)bx * 256 + wm * 128 + fm * 16 + kg * 4 + q;
        int gcol = by * 256 + wn * 64 + fn * 16 + lr;
        if (OUTF32)
          ((float*)Cg)[z * zC + grow * ldc + gcol] = acc[fm][fn][q];
        else
          ((f16*)Cg)[z * zC + grow * ldc + gcol] = (f16)acc[fm][fn][q];
      }
#undef STAGE
#undef LOAD_A
#undef LOAD_B
#undef DOMFMA
}

// ---------------------------------------------------------------------------
// Row softmax: SC row (2048 f32) -> Pb row (2048 f16)
// ---------------------------------------------------------------------------
__global__ __launch_bounds__(256)
void softmax_rows(const float* __restrict__ SC, f16* __restrict__ Pb) {
  const float* r = SC + (size_t)blockIdx.x * 2048;
  f16* po = Pb + (size_t)blockIdx.x * 2048;
  const int tid = threadIdx.x;
  f32x4 a = *(const f32x4*)(r + tid * 8);
  f32x4 b = *(const f32x4*)(r + tid * 8 + 4);
  float x[8] = {a[0], a[1], a[2], a[3], b[0], b[1], b[2], b[3]};
#pragma unroll
  for (int i = 0; i < 8; i++) x[i] = fminf(fmaxf(x[i], -1e30f), 1e30f);
  float m = x[0];
#pragma unroll
  for (int i = 1; i < 8; i++) m = fmaxf(m, x[i]);
#pragma unroll
  for (int off = 32; off; off >>= 1) m = fmaxf(m, __shfl_xor(m, off));
  __shared__ float rmax[4], rsum[4];
  const int w = tid >> 6, lane = tid & 63;
  if (!lane) rmax[w] = m;
  __syncthreads();
  m = fmaxf(fmaxf(rmax[0], rmax[1]), fmaxf(rmax[2], rmax[3]));
  float e[8], s = 0.f;
#pragma unroll
  for (int i = 0; i < 8; i++) {
    e[i] = __expf(x[i] - m);
    s += e[i];
  }
#pragma unroll
  for (int off = 32; off; off >>= 1) s += __shfl_xor(s, off);
  if (!lane) rsum[w] = s;
  __syncthreads();
  s = rsum[0] + rsum[1] + rsum[2] + rsum[3];
  float inv = 1.0f / s;
  f16x8 p;
#pragma unroll
  for (int i = 0; i < 8; i++) p[i] = (f16)(e[i] * inv);
  *(f16x8*)(po + tid * 8) = p;
}

// ---------------------------------------------------------------------------
extern "C" void kernel_launch(void* const* d_in, const int* in_sizes, int n_in,
                              void* d_out, int out_size, void* d_ws, size_t ws_size,
                              hipStream_t stream) {
  const float* S1 = (const float*)d_in[0];
  const float* S2 = (const float*)d_in[1];
  const float* W1 = (const float*)d_in[2];
  const float* W2 = (const float*)d_in[3];
  float* out = (float*)d_out;
  const int B = 8, N = 2048, H = 1024;
  const size_t NH = (size_t)N * H;  // 2M elems
  const size_t NN = (size_t)N * N;  // 4M elems
  const size_t WN = (size_t)H * H;  // 1M elems

  char* ws = (char*)d_ws;
  f16* W1h = (f16*)ws;
  f16* W2h = W1h + WN;
  size_t fixed = 2 * WN * sizeof(f16);  // 4 MB
  size_t perb = 5 * NH * sizeof(f16) + NN * sizeof(float) + NN * sizeof(f16);

  int bc = 1;
  const int cands[4] = {8, 4, 2, 1};
  for (int ci = 0; ci < 4; ci++) {
    if (fixed + (size_t)cands[ci] * perb <= ws_size) { bc = cands[ci]; break; }
  }
  f16* Ah = (f16*)(ws + fixed);       // S1 chunk f16
  f16* Bh = Ah + (size_t)bc * NH;     // S2 chunk f16
  f16* At = Bh + (size_t)bc * NH;     // S1 chunk transposed f16 [z][1024][2048]
  f16* Bt = At + (size_t)bc * NH;     // S2 chunk transposed
  f16* Kh = Bt + (size_t)bc * NH;     // proj output
  float* SC = (float*)(Kh + (size_t)bc * NH);
  f16* Pb = (f16*)(SC + (size_t)bc * NN);

  {
    int n4 = (int)(WN / 4);
    tof16x2_kernel<<<dim3((n4 + 255) / 256, 2), 256, 0, stream>>>(
        W1, W2, W1h, W2h, n4);
  }

  for (int c0 = 0; c0 < B; c0 += bc) {
    prep2_f16_kernel<<<dim3(N / 64, H / 64, 2 * bc), 256, 0, stream>>>(
        S1 + (size_t)c0 * NH, S2 + (size_t)c0 * NH, Ah, At, Bh, Bt, bc);

    for (int path = 0; path < 2; path++) {
      const f16* Qh = path ? Bh : Ah;  // query side (f16)
      const f16* Xh = path ? Ah : Bh;  // proj input (f16)
      const f16* Vt = path ? At : Bt;  // V transposed [z][1024][2048]
      const f16* Wh = path ? W2h : W1h;
      float* Op = out + (size_t)path * B * NH + (size_t)c0 * NH;

      // Kh = Xh @ W^T : M = bc*2048, N = 1024, K = 1024  (ZB=1, gx=bc*8)
      gemm256<0><<<dim3(bc * 32), 512, 0, stream>>>(
          Xh, 0, Wh, 0, Kh, 0, H, H, H, H, 1, bc * 8);
      // SC = Qh @ Kh^T per batch: 2048x2048, K = 1024  (ZB=bc, gx=8)
      gemm256<1><<<dim3(bc * 64), 512, 0, stream>>>(
          Qh, NH, Kh, NH, SC, NN, H, H, N, H, bc, 8);
      // softmax rows -> Pb f16
      softmax_rows<<<dim3(bc * N), 256, 0, stream>>>(SC, Pb);
      // O = Pb @ Vt^T : per batch 2048x1024, K = 2048  (ZB=bc, gx=8)
      gemm256<1><<<dim3(bc * 32), 512, 0, stream>>>(
          Pb, NN, Vt, NH, Op, NH, N, N, H, N, bc, 8);
    }
  }
}